// Round 6
// baseline (117.644 us; speedup 1.0000x reference)
//
#include <hip/hip_runtime.h>
#include <math.h>

#define S_DIM 256
#define B_DIM 16
#define F_DIM 200
#define H_DIM 100
#define ROWS (S_DIM * B_DIM)  // 4096

// ---------------------------------------------------------------------------
// K1: Eq = exp(2*(x@Wq)), Ek = exp(2*(x@Wk + b)) per row r = s*B+b.
// 8 rows/block, 256 threads = 2 f-halves x 128 h-lanes. fg forced to SGPR so
// the x row reads compile to s_load_dwordx4 (scalar pipe); W reads are
// coalesced vector loads.
// ---------------------------------------------------------------------------
__global__ __launch_bounds__(256) void k1_proj_exp(
    const float* __restrict__ input, const float* __restrict__ Wq,
    const float* __restrict__ Wk, const float* __restrict__ bias,
    float* __restrict__ Eq, float* __restrict__ Ek)
{
    __shared__ float pq[8][128], pk[8][128];
    const int tid = threadIdx.x;
    const int h = tid & 127;
    const int fg = __builtin_amdgcn_readfirstlane(tid >> 7);  // wave-uniform
    const int hh = (h < H_DIM) ? h : (H_DIM - 1);
    const int r0 = blockIdx.x * 8;
    float accq[8], acck[8];
#pragma unroll
    for (int r = 0; r < 8; ++r) { accq[r] = 0.f; acck[r] = 0.f; }
    const int fb = fg * 100;
    for (int f4 = 0; f4 < 25; ++f4) {
        const int f = fb + f4 * 4;
        const float wq0 = Wq[(f + 0) * H_DIM + hh];
        const float wq1 = Wq[(f + 1) * H_DIM + hh];
        const float wq2 = Wq[(f + 2) * H_DIM + hh];
        const float wq3 = Wq[(f + 3) * H_DIM + hh];
        const float wk0 = Wk[(f + 0) * H_DIM + hh];
        const float wk1 = Wk[(f + 1) * H_DIM + hh];
        const float wk2 = Wk[(f + 2) * H_DIM + hh];
        const float wk3 = Wk[(f + 3) * H_DIM + hh];
#pragma unroll
        for (int r = 0; r < 8; ++r) {
            // uniform address -> s_load_dwordx4
            const float4 xv = *(const float4*)&input[(r0 + r) * F_DIM + f];
            accq[r] = fmaf(xv.x, wq0, accq[r]);
            accq[r] = fmaf(xv.y, wq1, accq[r]);
            accq[r] = fmaf(xv.z, wq2, accq[r]);
            accq[r] = fmaf(xv.w, wq3, accq[r]);
            acck[r] = fmaf(xv.x, wk0, acck[r]);
            acck[r] = fmaf(xv.y, wk1, acck[r]);
            acck[r] = fmaf(xv.z, wk2, acck[r]);
            acck[r] = fmaf(xv.w, wk3, acck[r]);
        }
    }
    if (fg) {
#pragma unroll
        for (int r = 0; r < 8; ++r) { pq[r][h] = accq[r]; pk[r][h] = acck[r]; }
    }
    __syncthreads();
    if (!fg && h < H_DIM) {
        const float bv = bias[h];
#pragma unroll
        for (int r = 0; r < 8; ++r) {
            const float q = accq[r] + pq[r][h];
            const float k = acck[r] + pk[r][h] + bv;
            Eq[(r0 + r) * H_DIM + h] = __expf(2.f * q);
            Ek[(r0 + r) * H_DIM + h] = __expf(2.f * k);
        }
    }
}

// ---------------------------------------------------------------------------
// K2: scores. 2-way fused denominators: 6 VALU + 1 rcp per 2 h-elements.
// th via readfirstlane so Eq row loads are s_load_dwordx4 (round-5 dropped
// this — they silently became same-address vector loads). Epilogue stages the
// 64s x 8t tile in LDS and stores p PACKED as [b][s/4][t][4] so K3's per-lane
// read is one coalesced dwordx4 spanning 4 s-steps. Each wave's store covers
// two contiguous 128B segments.
// ---------------------------------------------------------------------------
__global__ __launch_bounds__(256) void k2_scores(
    const float* __restrict__ Eq, const float* __restrict__ Ek,
    const float* __restrict__ vvec, const int* __restrict__ seqlen,
    float* __restrict__ p4)
{
    __shared__ float4 klds[64 * 27];
    __shared__ float pt[64][9];
    const int tid = threadIdx.x;
    const int b = blockIdx.z;
    const int len = seqlen[b];
    const int s0 = blockIdx.y * 64;
    const int t0 = blockIdx.x * 8;
    if (s0 >= len || t0 >= len) return;  // block-uniform, before any barrier
    const float4* Ek4 = (const float4*)Ek;
    for (int idx = tid; idx < 64 * 25; idx += 256) {
        int r = idx / 25, c = idx - r * 25;
        klds[r * 27 + c] = Ek4[((s0 + r) * B_DIM + b) * 25 + c];
    }
    __syncthreads();
    const int s = tid & 63;
    const int th = __builtin_amdgcn_readfirstlane(tid >> 6);  // wave-uniform
    const int tbase = t0 + th * 2;  // <= 255 always

    float sv = 0.f;
    for (int h4 = 0; h4 < 25; ++h4) {
        const float4 vv = *(const float4*)&vvec[h4 * 4];
        sv += (vv.x + vv.y) + (vv.z + vv.w);
    }
    float acc0 = sv, acc1 = sv;
    const float* eq0 = Eq + ((tbase + 0) * B_DIM + b) * H_DIM;
    const float* eq1 = Eq + ((tbase + 1) * B_DIM + b) * H_DIM;
    for (int h4 = 0; h4 < 25; ++h4) {
        const float4 kk = klds[s * 27 + h4];
        const float4 vv = *(const float4*)&vvec[h4 * 4];
        const float4 q0 = *(const float4*)(eq0 + h4 * 4);  // s_load
        const float4 q1 = *(const float4*)(eq1 + h4 * 4);  // s_load
        const float vmx = -2.f * vv.x, vmy = -2.f * vv.y;
        const float vmz = -2.f * vv.z, vmw = -2.f * vv.w;
        {
            float dx = fmaf(q0.x, kk.x, 1.f), dy = fmaf(q0.y, kk.y, 1.f);
            float N = fmaf(vmx, dy, vmy * dx);
            acc0 = fmaf(N, __builtin_amdgcn_rcpf(dx * dy), acc0);
            float dz = fmaf(q0.z, kk.z, 1.f), dw = fmaf(q0.w, kk.w, 1.f);
            float M = fmaf(vmz, dw, vmw * dz);
            acc0 = fmaf(M, __builtin_amdgcn_rcpf(dz * dw), acc0);
        }
        {
            float dx = fmaf(q1.x, kk.x, 1.f), dy = fmaf(q1.y, kk.y, 1.f);
            float N = fmaf(vmx, dy, vmy * dx);
            acc1 = fmaf(N, __builtin_amdgcn_rcpf(dx * dy), acc1);
            float dz = fmaf(q1.z, kk.z, 1.f), dw = fmaf(q1.w, kk.w, 1.f);
            float M = fmaf(vmz, dw, vmw * dz);
            acc1 = fmaf(M, __builtin_amdgcn_rcpf(dz * dw), acc1);
        }
    }
    pt[s][th * 2 + 0] = __expf(acc0);
    pt[s][th * 2 + 1] = __expf(acc1);
    __syncthreads();
    // packed store: p4[b][(s0+sl)>>2][t0+tr][sl&3]
    float* pb = p4 + ((b * 64 + (s0 >> 2)) * S_DIM + t0) * 4;
#pragma unroll
    for (int v = tid; v < 512; v += 256) {
        const int scl = v >> 5, rem = v & 31, tr = rem >> 2, q = rem & 3;
        const int sl = scl * 4 + q;
        if (s0 + sl < len) pb[(scl * S_DIM + tr) * 4 + q] = pt[sl][tr];
    }
}

// ---------------------------------------------------------------------------
// K3: attended + normalize + full pool, ONE block per (f-tile of 8, b).
// lane = t. p read as [b][sc][t][4]: one coalesced global_load_dwordx4 per
// lane covers 4 s-steps (4x fewer VMEM instrs than round 5); 8-s unroll keeps
// 2 independent loads in flight. x[s][f0..7] staged once in 8 KB LDS, read
// via same-address broadcast ds_read_b128. Pool: butterfly + 4-wave LDS
// combine -> writes out directly.
// ---------------------------------------------------------------------------
__global__ __launch_bounds__(256) void k3_attend_pool(
    const float* __restrict__ p4, const float* __restrict__ input,
    const int* __restrict__ seqlen, float* __restrict__ out)
{
    __shared__ float4 xlds4[512];  // [s][2] : x[s][b][f0..f0+7]
    __shared__ float lm[4][8], ls[4][8];
    const int tid = threadIdx.x;
    const int b = blockIdx.y;
    const int len = seqlen[b];
    const int base = b * 50 + blockIdx.x * 2;  // float4 index of x[s=0][b][f0]
    const float4* in4 = (const float4*)input;
    for (int i = tid; i < 512; i += 256) {
        const int s = i >> 1, half = i & 1;
        xlds4[i] = in4[s * (B_DIM * 50) + base + half];
    }
    __syncthreads();

    float acc[8];
#pragma unroll
    for (int j = 0; j < 8; ++j) acc[j] = 0.f;
    float psum = 0.f;
    const float4* pb4 = (const float4*)p4 + b * (64 * S_DIM) + tid;  // + sc*256

#define K3_STEP(pv, sbase)                                  \
    do {                                                    \
        const float4 xa = xlds4[(sbase) * 2];               \
        const float4 xb = xlds4[(sbase) * 2 + 1];           \
        psum += (pv);                                       \
        acc[0] = fmaf((pv), xa.x, acc[0]);                  \
        acc[1] = fmaf((pv), xa.y, acc[1]);                  \
        acc[2] = fmaf((pv), xa.z, acc[2]);                  \
        acc[3] = fmaf((pv), xa.w, acc[3]);                  \
        acc[4] = fmaf((pv), xb.x, acc[4]);                  \
        acc[5] = fmaf((pv), xb.y, acc[5]);                  \
        acc[6] = fmaf((pv), xb.z, acc[6]);                  \
        acc[7] = fmaf((pv), xb.w, acc[7]);                  \
    } while (0)

    const int nfull = len >> 2;  // complete 4-s groups
    int sc = 0;
    for (; sc + 2 <= nfull; sc += 2) {  // 8 s per iter, 2 loads in flight
        const float4 pa = pb4[sc * S_DIM];
        const float4 pc = pb4[(sc + 1) * S_DIM];
        const int sb = sc * 4;
        K3_STEP(pa.x, sb + 0); K3_STEP(pa.y, sb + 1);
        K3_STEP(pa.z, sb + 2); K3_STEP(pa.w, sb + 3);
        K3_STEP(pc.x, sb + 4); K3_STEP(pc.y, sb + 5);
        K3_STEP(pc.z, sb + 6); K3_STEP(pc.w, sb + 7);
    }
    if (sc < nfull) {  // one more complete group
        const float4 pa = pb4[sc * S_DIM];
        const int sb = sc * 4;
        K3_STEP(pa.x, sb + 0); K3_STEP(pa.y, sb + 1);
        K3_STEP(pa.z, sb + 2); K3_STEP(pa.w, sb + 3);
        ++sc;
    }
    for (int s = nfull * 4; s < len; ++s) {  // tail 0..3 scalar
        const float pv = p4[((b * 64 + (s >> 2)) * S_DIM + tid) * 4 + (s & 3)];
        K3_STEP(pv, s);
    }
#undef K3_STEP

    // normalize + pool over t (lane dimension)
    const float rp = __builtin_amdgcn_rcpf(psum);
    const bool ok = (tid < len);
    const int w = tid >> 6, lane = tid & 63;
#pragma unroll
    for (int j = 0; j < 8; ++j) {
        const float a = acc[j] * rp;
        float m = ok ? a : -INFINITY;
        float s2 = ok ? a : 0.f;
        for (int off = 32; off; off >>= 1) {
            m = fmaxf(m, __shfl_xor(m, off));
            s2 += __shfl_xor(s2, off);
        }
        if (lane == 0) { lm[w][j] = m; ls[w][j] = s2; }
    }
    __syncthreads();
    if (tid < 8) {
        float m = lm[0][tid], s2 = ls[0][tid];
#pragma unroll
        for (int g = 1; g < 4; ++g) { m = fmaxf(m, lm[g][tid]); s2 += ls[g][tid]; }
        const int f0 = blockIdx.x * 8;
        out[b * (2 * F_DIM) + f0 + tid] = m;
        out[b * (2 * F_DIM) + F_DIM + f0 + tid] = s2 / (float)len;
    }
}

extern "C" void kernel_launch(void* const* d_in, const int* in_sizes, int n_in,
                              void* d_out, int out_size, void* d_ws, size_t ws_size,
                              hipStream_t stream)
{
    const float* input  = (const float*)d_in[0];
    const int*   seqlen = (const int*)d_in[1];
    const float* Wq     = (const float*)d_in[2];
    const float* Wk     = (const float*)d_in[3];
    const float* bias   = (const float*)d_in[4];
    const float* vvec   = (const float*)d_in[5];
    float* out = (float*)d_out;

    float* ws = (float*)d_ws;
    float* Eq = ws;                 // 409600 floats
    float* Ek = ws + 409600;        // 409600 floats
    float* p4 = ws + 819200;        // 1048576 floats, layout [b][s/4][t][4]

    k1_proj_exp<<<ROWS / 8, 256, 0, stream>>>(input, Wq, Wk, bias, Eq, Ek);
    k2_scores<<<dim3(S_DIM / 8, S_DIM / 64, B_DIM), 256, 0, stream>>>(Eq, Ek, vvec, seqlen, p4);
    k3_attend_pool<<<dim3(F_DIM / 8, B_DIM), 256, 0, stream>>>(p4, input, seqlen, out);
}